// Round 1
// baseline (15.263 us; speedup 1.0000x reference)
//
#include <hip/hip_runtime.h>

// out[n,d,oc,r] = logsumexp_ic( x[n,0,d,ic,r] + w[d,ic,oc,r] )
//              = log( sum_ic exp(x) * exp(w) )   (no max-shift needed: |x+w| <~ 12)
//
// N=256, D=64, IC=32, OC=32, R=8. fp32 in/out.
// Block: 256 threads = one d x 16 n. Stage exp(w[d]) and exp(x) in LDS once,
// one barrier, then 4n x 4oc register-blocked dot products over ic.

constexpr int kN = 256, kD = 64, kIC = 32, kOC = 32, kR = 8;
constexpr int kNT = 16;   // n rows per block
constexpr int PAD = 36;   // padded row length (floats); 36*4B rows keep all LDS
                          // phases <=2-way bank aliasing (free) and are 16B aligned

__global__ __launch_bounds__(256) void lse_kernel(
    const float* __restrict__ x, const float* __restrict__ w,
    float* __restrict__ out)
{
    __shared__ __align__(16) float ws[kIC * kR * PAD];   // exp(w), [ic][r][oc+pad]  36 KiB
    __shared__ __align__(16) float xs[kNT * kR * PAD];   // exp(x), [n][r][ic+pad]   18 KiB

    const int t  = threadIdx.x;
    const int d  = blockIdx.x;
    const int n0 = blockIdx.y * kNT;

    // ---- stage exp(weights[d]): global [ic][oc][r] -> LDS [ic][r][oc]
    {
        const float4* wg = reinterpret_cast<const float4*>(w + (size_t)d * (kIC * kOC * kR));
        #pragma unroll
        for (int i = 0; i < 8; ++i) {
            float4 v = wg[i * 256 + t];
            int lin = (i * 256 + t) * 4;   // flat float idx within [ic][oc][r]
            int ic = lin >> 8;
            int oc = (lin >> 3) & 31;
            int r  = lin & 7;              // components cover r..r+3 (same ic,oc)
            float* p = &ws[(ic * kR + r) * PAD + oc];
            p[0 * PAD] = __expf(v.x);
            p[1 * PAD] = __expf(v.y);
            p[2 * PAD] = __expf(v.z);
            p[3 * PAD] = __expf(v.w);
        }
    }

    // ---- stage exp(x[n0..n0+15, d]): global [ic][r] -> LDS [n][r][ic]
    {
        #pragma unroll
        for (int i = 0; i < 4; ++i) {
            int fidx = i * 256 + t;        // float4 index across the 16 rows
            int ns = fidx >> 6;            // which n (0..15)
            int e  = fidx & 63;            // float4 within the 256-float row
            const float4* xg = reinterpret_cast<const float4*>(
                x + (size_t)(n0 + ns) * (kD * kIC * kR) + (size_t)d * (kIC * kR));
            float4 v = xg[e];
            int lin = e * 4;               // [ic][r]: lin = ic*8 + r
            int ic = lin >> 3;
            int r  = lin & 7;              // components cover r..r+3 (same ic)
            float* p = &xs[(ns * kR + r) * PAD + ic];
            p[0 * PAD] = __expf(v.x);
            p[1 * PAD] = __expf(v.y);
            p[2 * PAD] = __expf(v.z);
            p[3 * PAD] = __expf(v.w);
        }
    }

    __syncthreads();

    // ---- compute: thread owns (nq, ocq, rr): 4 n (nq*4+jj) x 4 oc (k*8+ocq)
    const int rr  = t & 7;
    const int ocq = (t >> 3) & 7;
    const int nq  = t >> 6;                // wave id: each wave owns 4 n rows

    float acc[4][4];
    #pragma unroll
    for (int jj = 0; jj < 4; ++jj)
        #pragma unroll
        for (int k = 0; k < 4; ++k)
            acc[jj][k] = 0.f;

    const float4* xs4 = reinterpret_cast<const float4*>(xs);  // row = 9 float4
    #pragma unroll
    for (int icq = 0; icq < 8; ++icq) {
        float4 xv[4];
        #pragma unroll
        for (int jj = 0; jj < 4; ++jj)
            xv[jj] = xs4[((nq * 4 + jj) * kR + rr) * (PAD / 4) + icq];
        #pragma unroll
        for (int q = 0; q < 4; ++q) {
            const int ic = icq * 4 + q;
            float wv[4];
            #pragma unroll
            for (int k = 0; k < 4; ++k)
                wv[k] = ws[(ic * kR + rr) * PAD + k * 8 + ocq];
            #pragma unroll
            for (int jj = 0; jj < 4; ++jj) {
                const float* xvp = reinterpret_cast<const float*>(&xv[jj]);
                const float xq = xvp[q];
                #pragma unroll
                for (int k = 0; k < 4; ++k)
                    acc[jj][k] = fmaf(xq, wv[k], acc[jj][k]);
            }
        }
    }

    // ---- store: addr = n*16384 + d*256 + (k*8+ocq)*8 + rr -> per-instr 256B contiguous
    #pragma unroll
    for (int jj = 0; jj < 4; ++jj) {
        const int n = n0 + nq * 4 + jj;
        float* op = out + (size_t)n * (kD * kOC * kR) + (size_t)d * (kOC * kR) + rr;
        #pragma unroll
        for (int k = 0; k < 4; ++k)
            op[(k * 8 + ocq) * 8] = __logf(acc[jj][k]);
    }
}

extern "C" void kernel_launch(void* const* d_in, const int* in_sizes, int n_in,
                              void* d_out, int out_size, void* d_ws, size_t ws_size,
                              hipStream_t stream) {
    const float* x = (const float*)d_in[0];
    const float* w = (const float*)d_in[1];
    float* out = (float*)d_out;
    dim3 grid(kD, kN / kNT);
    lse_kernel<<<grid, 256, 0, stream>>>(x, w, out);
}

// Round 2
// 15.031 us; speedup vs baseline: 1.0154x; 1.0154x over previous
//
#include <hip/hip_runtime.h>

// out[n,d,oc,r] = logsumexp_ic( x[n,0,d,ic,r] + w[d,ic,oc,r] )
//              = log( sum_ic exp(x) * exp(w) )   (no max-shift: |x+w| <~ 12)
//
// N=256, D=64, IC=32, OC=32, R=8. fp32 in/out.
// Block = one d x 32 n, 256 threads. Grid = 64 x 8 = 512 blocks = exactly
// 2 blocks/CU (LDS 72 KiB -> 2 resident). Thread tile = 4n x 8oc x 1r.
// All compute-phase LDS reads are ds_read_b128 (ws stored oc-permuted).

constexpr int kN = 256, kD = 64, kIC = 32, kOC = 32, kR = 8;
constexpr int kNT = 32;   // n rows per block
constexpr int PAD = 36;   // floats per LDS row (32 data + 4 pad): 16B-aligned,
                          // rr*36 mod 32 = 4*rr spreads rows across banks
constexpr int PQ  = PAD / 4;

__global__ __launch_bounds__(256) void lse_kernel(
    const float* __restrict__ x, const float* __restrict__ w,
    float* __restrict__ out)
{
    // ws row (ic*8+r): position j holds oc = (j&7)*4 + (j>>3)  [j = (oc&3)*8 + (oc>>2)]
    // -> thread och reads quads {och*2, och*2+1} = its 8 oc as two float4
    __shared__ __align__(16) float ws[kIC * kR * PAD];   // 36 KiB
    __shared__ __align__(16) float xs[kNT * kR * PAD];   // 36 KiB, [nl*8+r][ic]

    const int t  = threadIdx.x;
    const int d  = blockIdx.x;
    const int n0 = blockIdx.y * kNT;

    // ---- stage exp(weights[d]): global [ic][oc][r] -> ws
    {
        const float4* wg = reinterpret_cast<const float4*>(w + (size_t)d * (kIC * kOC * kR));
        #pragma unroll
        for (int i = 0; i < 8; ++i) {
            const int qg = i * 256 + t;
            float4 v = wg[qg];
            const int lin = qg * 4;
            const int ic = lin >> 8;
            const int oc = (lin >> 3) & 31;
            const int r0 = lin & 7;              // 0 or 4; components r0..r0+3
            const int j  = (oc & 3) * 8 + (oc >> 2);
            float* p = &ws[(ic * kR + r0) * PAD + j];
            p[0 * PAD] = __expf(v.x);
            p[1 * PAD] = __expf(v.y);
            p[2 * PAD] = __expf(v.z);
            p[3 * PAD] = __expf(v.w);
        }
    }

    // ---- stage exp(x[n0..n0+31, d]): global [ic][r] -> xs [nl][r][ic]
    {
        #pragma unroll
        for (int i = 0; i < 8; ++i) {
            const int fidx = i * 256 + t;
            const int nl = fidx >> 6;            // 0..31
            const int e  = fidx & 63;            // float4 within 256-float row
            const float4* xg = reinterpret_cast<const float4*>(
                x + (size_t)(n0 + nl) * (kD * kIC * kR) + (size_t)d * (kIC * kR));
            float4 v = xg[e];
            const int ic = e >> 1;
            const int r0 = (e & 1) * 4;          // components r0..r0+3
            float* p = &xs[(nl * kR + r0) * PAD + ic];
            p[0 * PAD] = __expf(v.x);
            p[1 * PAD] = __expf(v.y);
            p[2 * PAD] = __expf(v.z);
            p[3 * PAD] = __expf(v.w);
        }
    }

    __syncthreads();

    // ---- compute: thread (rr, och, ng) owns 4 n (ng*4+jj) x 8 oc (k*4+och) x r=rr
    const int rr  = t & 7;
    const int och = (t >> 3) & 3;
    const int ng  = t >> 5;

    float acc[4][8];
    #pragma unroll
    for (int jj = 0; jj < 4; ++jj)
        #pragma unroll
        for (int k = 0; k < 8; ++k)
            acc[jj][k] = 0.f;

    const float4* xs4 = reinterpret_cast<const float4*>(xs);
    const float4* ws4 = reinterpret_cast<const float4*>(ws);

    #pragma unroll
    for (int icq = 0; icq < 8; ++icq) {
        float4 xv[4];
        #pragma unroll
        for (int jj = 0; jj < 4; ++jj)
            xv[jj] = xs4[((ng * 4 + jj) * kR + rr) * PQ + icq];
        #pragma unroll
        for (int q = 0; q < 4; ++q) {
            const int ic = icq * 4 + q;
            const float4 w0 = ws4[(ic * kR + rr) * PQ + och * 2];
            const float4 w1 = ws4[(ic * kR + rr) * PQ + och * 2 + 1];
            #pragma unroll
            for (int jj = 0; jj < 4; ++jj) {
                const float* xp = reinterpret_cast<const float*>(&xv[jj]);
                const float xq = xp[q];
                acc[jj][0] = fmaf(xq, w0.x, acc[jj][0]);
                acc[jj][1] = fmaf(xq, w0.y, acc[jj][1]);
                acc[jj][2] = fmaf(xq, w0.z, acc[jj][2]);
                acc[jj][3] = fmaf(xq, w0.w, acc[jj][3]);
                acc[jj][4] = fmaf(xq, w1.x, acc[jj][4]);
                acc[jj][5] = fmaf(xq, w1.y, acc[jj][5]);
                acc[jj][6] = fmaf(xq, w1.z, acc[jj][6]);
                acc[jj][7] = fmaf(xq, w1.w, acc[jj][7]);
            }
        }
    }

    // ---- store: addr = n*16384 + d*256 + (k*4+och)*8 + rr
    //      per (jj,k) instr: lanes (rr,och) cover 128B contiguous x 2 ng-rows
    #pragma unroll
    for (int jj = 0; jj < 4; ++jj) {
        const int n = n0 + ng * 4 + jj;
        float* op = out + (size_t)n * (kD * kOC * kR) + (size_t)d * (kOC * kR)
                    + och * 8 + rr;
        #pragma unroll
        for (int k = 0; k < 8; ++k)
            op[k * 32] = __logf(acc[jj][k]);
    }
}

extern "C" void kernel_launch(void* const* d_in, const int* in_sizes, int n_in,
                              void* d_out, int out_size, void* d_ws, size_t ws_size,
                              hipStream_t stream) {
    const float* x = (const float*)d_in[0];
    const float* w = (const float*)d_in[1];
    float* out = (float*)d_out;
    dim3 grid(kD, kN / kNT);
    lse_kernel<<<grid, 256, 0, stream>>>(x, w, out);
}